// Round 1
// baseline (382.295 us; speedup 1.0000x reference)
//
#include <hip/hip_runtime.h>
#include <hip/hip_fp16.h>

#define HF 32
#define EPS 1e-5f
#define BSH 7
#define BSZ 128          // nodes per bucket
#define CH  4096         // edges per binning block (single-pass, fits in regs)
#define SUBCAP 512       // per-XCD sub-segment capacity
#define CAP (8*SUBCAP)   // bucket segment capacity (4096)

typedef int vi4 __attribute__((ext_vector_type(4)));

__device__ __forceinline__ float leaky(float v){ return fmaxf(v, 0.01f*v); }
__device__ __forceinline__ float elu1(float v){ return v > 0.f ? v : (expf(v)-1.f); }
__device__ __forceinline__ float sigmoidf(float v){ return 1.f/(1.f+expf(-v)); }

// nt 16B index load (read-once stream). NOTE: nt LOADS only — nt stores on
// scattered writes caused 143MB HBM writeback in a previous round.
__device__ __forceinline__ int4 nt_load_i4(const int* p){
    vi4 v = __builtin_nontemporal_load((const vi4*)p);
    return make_int4(v.x, v.y, v.z, v.w);
}

// add 8 halfs (16B) into fp32 accumulator
__device__ __forceinline__ void addrow8(float* a, float4 v){
    const __half2* p = (const __half2*)&v;
#pragma unroll
    for (int k = 0; k < 4; k++){
        float2 f = __half22float2(p[k]);
        a[2*k] += f.x; a[2*k+1] += f.y;
    }
}
// packed fp16 add of two 8-half rows
__device__ __forceinline__ float4 h2add4f(float4 a, float4 b){
    __half2* pa = (__half2*)&a; __half2* pb = (__half2*)&b;
    float4 r; __half2* pr = (__half2*)&r;
#pragma unroll
    for (int k = 0; k < 4; k++) pr[k] = __hadd2(pa[k], pb[k]);
    return r;
}

// ===== fused: edge binning (single pass) | input MLP + BN stats ============
// bin blocks FIRST in the grid so their latency overlaps MLP compute.
union SMem {
    struct {
        float sW1[3*HF]; float sB1[HF]; float sW2[HF*HF]; float sB2[HF];
        float sh[256][33];
    } mlp;
    struct { int lcnt[1024]; int lbase[1024]; int lpos[1024]; } bin;
};

__global__ __launch_bounds__(256)
void k_mlp_bin(const float* __restrict__ x,
               const float* __restrict__ w1, const float* __restrict__ b1,
               const float* __restrict__ w2, const float* __restrict__ b2,
               __half* __restrict__ h, float* __restrict__ stats,
               const int* __restrict__ src, const int* __restrict__ dst,
               int* __restrict__ gfill, int* __restrict__ ep,
               int* __restrict__ deg,
               int N, int E, int B, int NC){
    __shared__ SMem sm;
    int t = threadIdx.x;
    if ((int)blockIdx.x < NC){
        // ---------------- binning: single pass, chunk held in regs --------
        int bid = blockIdx.x;
        for (int i = t; i < B; i += 256){ sm.bin.lcnt[i] = 0; sm.bin.lpos[i] = 0; }
        __syncthreads();
        int base = bid * CH;
        int xcd = bid & 7;
        int dv[16], sv[16];
        if (base + CH <= E){
#pragma unroll
            for (int i = 0; i < 4; i++){
                int4 d4 = nt_load_i4(dst + base + (t + i*256)*4);
                int4 s4 = nt_load_i4(src + base + (t + i*256)*4);
                dv[4*i]   = d4.x; dv[4*i+1] = d4.y; dv[4*i+2] = d4.z; dv[4*i+3] = d4.w;
                sv[4*i]   = s4.x; sv[4*i+1] = s4.y; sv[4*i+2] = s4.z; sv[4*i+3] = s4.w;
            }
        } else {
#pragma unroll
            for (int i = 0; i < 16; i++){
                int e = base + t + i*256;
                dv[i] = (e < E) ? dst[e] : -1;
                sv[i] = (e < E) ? src[e] : 0;
            }
        }
#pragma unroll
        for (int i = 0; i < 16; i++)
            if (dv[i] >= 0){
                atomicAdd(&sm.bin.lcnt[dv[i] >> BSH], 1);
                atomicAdd(&deg[dv[i]], 1);          // fire-and-forget global
            }
        __syncthreads();
        // reserve contiguous range in this block's xcd sub-segment per bucket
        for (int i = t; i < B; i += 256){
            int c = sm.bin.lcnt[i];
            sm.bin.lbase[i] = c ? (i*CAP + xcd*SUBCAP + atomicAdd(&gfill[i*8 + xcd], c)) : 0;
        }
        __syncthreads();
        // scatter straight from registers (no re-read)
#pragma unroll
        for (int i = 0; i < 16; i++)
            if (dv[i] >= 0){
                int bb = dv[i] >> BSH;
                int p = sm.bin.lbase[bb] + atomicAdd(&sm.bin.lpos[bb], 1);
                ep[p] = (sv[i] << BSH) | (dv[i] & (BSZ-1));
            }
    } else {
        // ---------------- MLP + BN stats ----------------
        for (int i = t; i < 3*HF; i += 256) sm.mlp.sW1[i] = w1[i];
        if (t < HF){ sm.mlp.sB1[t] = b1[t]; sm.mlp.sB2[t] = b2[t]; }
        for (int i = t; i < HF*HF; i += 256) sm.mlp.sW2[i] = w2[i];
        __syncthreads();
        int n = (blockIdx.x - NC)*256 + t;
        float h2[HF];
        if (n < N){
            float x0 = x[(size_t)n*3], x1 = x[(size_t)n*3+1], x2 = x[(size_t)n*3+2];
            float h1[HF];
#pragma unroll
            for (int j = 0; j < HF; j++){
                float v = fmaf(x0, sm.mlp.sW1[j], fmaf(x1, sm.mlp.sW1[HF+j],
                          fmaf(x2, sm.mlp.sW1[2*HF+j], sm.mlp.sB1[j])));
                h1[j] = leaky(v);
            }
#pragma unroll
            for (int j = 0; j < HF; j++){
                float v = sm.mlp.sB2[j];
#pragma unroll
                for (int i = 0; i < HF; i++) v = fmaf(h1[i], sm.mlp.sW2[i*HF+j], v);
                h2[j] = leaky(v);
            }
            float4* hv = (float4*)(h + (size_t)n*HF);
#pragma unroll
            for (int jb = 0; jb < 4; jb++){
                __half2 hh[4];
#pragma unroll
                for (int k = 0; k < 4; k++)
                    hh[k] = __float22half2_rn(make_float2(h2[jb*8+2*k], h2[jb*8+2*k+1]));
                hv[jb] = *(float4*)hh;
            }
        } else {
#pragma unroll
            for (int j = 0; j < HF; j++) h2[j] = 0.f;
        }
#pragma unroll
        for (int j = 0; j < HF; j++) sm.mlp.sh[t][j] = h2[j];
        __syncthreads();
        int f = t & 31, g = t >> 5;
        float s = 0.f, ss = 0.f;
        for (int i = 0; i < 32; i++){
            float v = sm.mlp.sh[g*32 + i][f];
            s += v; ss += v*v;
        }
        __syncthreads();
        sm.mlp.sh[g][f] = s; sm.mlp.sh[8+g][f] = ss;
        __syncthreads();
        if (t < HF){
            float a = 0.f, b = 0.f;
#pragma unroll
            for (int g2 = 0; g2 < 8; g2++){ a += sm.mlp.sh[g2][t]; b += sm.mlp.sh[8+g2][t]; }
            atomicAdd(&stats[t], a);
            atomicAdd(&stats[HF+t], b);
        }
    }
}

// ===== fused: per-bucket CSR build (+degree-sorted order) | BN + t1 ========
// CSR blocks [0,B): read deg (no count pass), brute-force rank+prefix over
// 128 nodes in LDS, in-place sort of bucket segment, write rowp2/dis/norder.
// BN blocks [B, B+GBT): t1 = (bn(h)@W)*dis, dis recomputed from deg inline.
union SMem2 {
    struct { int sep[CAP]; int sdeg[128]; int spre[128]; int sfill[128]; } c;
    struct { float sW[HF*HF]; float sh[64][33]; } m;
};

__global__ __launch_bounds__(256)
void k_csr_bn(int* __restrict__ ep, const int* __restrict__ gfill,
              const int* __restrict__ deg,
              int2* __restrict__ rowp2, float* __restrict__ dis,
              int* __restrict__ norder,
              const __half* __restrict__ h, const float* __restrict__ stats,
              const float* __restrict__ gamma, const float* __restrict__ beta,
              const float* __restrict__ W, __half* __restrict__ tout,
              int N, int B){
    __shared__ SMem2 sm;
    int t = threadIdx.x;
    if ((int)blockIdx.x < B){
        int b = blockIdx.x;
        int cx[8], coff[8], cnt = 0;
#pragma unroll
        for (int xx = 0; xx < 8; xx++){ cx[xx] = gfill[b*8 + xx]; coff[xx] = cnt; cnt += cx[xx]; }
        int base = b*CAP;
#pragma unroll
        for (int xx = 0; xx < 8; xx++)
            for (int j = t; j < cx[xx]; j += 256) sm.c.sep[coff[xx] + j] = ep[base + xx*SUBCAP + j];
        if (t < 128){
            sm.c.sfill[t] = 0;
            int n = b*BSZ + t;
            sm.c.sdeg[t] = (n < N) ? deg[n] : 0;
        }
        __syncthreads();
        if (t < 128){
            int dg = sm.c.sdeg[t];
            int pre = 0, rank = 0;
            for (int j = 0; j < 128; j++){
                int dj = sm.c.sdeg[j];                 // LDS broadcast
                if (j < t) pre += dj;
                if (dj > dg || (dj == dg && j < t)) rank++;
            }
            sm.c.spre[t] = pre;
            int n = b*BSZ + t;
            if (n < N){
                rowp2[n] = make_int2(base + pre, base + pre + dg);
                dis[n]   = rsqrtf((float)dg + 1.0f);
                norder[b*BSZ + rank] = n;              // degree-descending order
            } else {
                norder[b*BSZ + rank] = -1;             // invalid slots sort last
            }
        }
        __syncthreads();
        for (int e = t; e < cnt; e += 256){
            int val = sm.c.sep[e];
            int d = val & (BSZ-1);
            int p = sm.c.spre[d] + atomicAdd(&sm.c.sfill[d], 1);
            ep[base + p] = val >> BSH;                 // strip -> plain src index
        }
    } else {
        // ---------------- BN + first transform ----------------
        for (int i = t; i < HF*HF; i += 256) sm.m.sW[i] = W[i];
        int nib = t >> 2, l = t & 3;
        int n = (blockIdx.x - B)*64 + nib;
        float hv[8];
        float d = 0.f;
        if (n < N){
            float4 raw = ((const float4*)h)[(size_t)n*4 + l];
            const __half2* p = (const __half2*)&raw;
            float tmp[8];
#pragma unroll
            for (int k = 0; k < 4; k++){
                float2 f2 = __half22float2(p[k]);
                tmp[2*k] = f2.x; tmp[2*k+1] = f2.y;
            }
            d = rsqrtf((float)deg[n] + 1.0f);
            float inv = 1.0f / (float)N;
#pragma unroll
            for (int c = 0; c < 8; c++){
                int f = 8*l + c;
                float mu  = stats[f]    * inv;
                float var = stats[HF+f] * inv - mu*mu;
                float rs  = rsqrtf(var + EPS);
                hv[c] = (tmp[c] - mu) * rs * gamma[f] + beta[f];
            }
        } else {
#pragma unroll
            for (int c = 0; c < 8; c++) hv[c] = 0.f;
        }
        __syncthreads();
#pragma unroll
        for (int c = 0; c < 8; c++) sm.m.sh[nib][8*l + c] = hv[c];
        __syncthreads();
        float o[8] = {0.f,0.f,0.f,0.f,0.f,0.f,0.f,0.f};
#pragma unroll
        for (int i = 0; i < HF; i++){
            float hvv = sm.m.sh[nib][i];
            float4 w0 = *(const float4*)&sm.m.sW[i*HF + 8*l];
            float4 w1 = *(const float4*)&sm.m.sW[i*HF + 8*l + 4];
            o[0] = fmaf(hvv, w0.x, o[0]); o[1] = fmaf(hvv, w0.y, o[1]);
            o[2] = fmaf(hvv, w0.z, o[2]); o[3] = fmaf(hvv, w0.w, o[3]);
            o[4] = fmaf(hvv, w1.x, o[4]); o[5] = fmaf(hvv, w1.y, o[5]);
            o[6] = fmaf(hvv, w1.z, o[6]); o[7] = fmaf(hvv, w1.w, o[7]);
        }
        if (n < N){
            __half2 hh[4];
#pragma unroll
            for (int k = 0; k < 4; k++)
                hh[k] = __float22half2_rn(make_float2(o[2*k]*d, o[2*k+1]*d));
            ((float4*)tout)[(size_t)n*4 + l] = *(float4*)hh;
        }
    }
}

// ------- per-node gather (degree-sorted order, 8-deep row loads) ------------
__global__ __launch_bounds__(256)
void k_gather_t(const __half* __restrict__ tin, const int* __restrict__ esrc,
                const int2* __restrict__ rowp2, const float* __restrict__ dis,
                const int* __restrict__ norder,
                const float* __restrict__ bias, const float* __restrict__ W,
                __half* __restrict__ tout, int N){
    __shared__ float sW[HF*HF];
    __shared__ float sh[64][33];
    int tid = threadIdx.x;
    for (int i = tid; i < HF*HF; i += 256) sW[i] = W[i];
    int nib = tid >> 2, l = tid & 3;
    int n = norder[blockIdx.x*64 + nib];
    float acc[8] = {0.f,0.f,0.f,0.f,0.f,0.f,0.f,0.f};
    float d = 0.f;
    const float4* tv = (const float4*)tin;
    if (n >= 0){
        addrow8(acc, tv[(size_t)n*4 + l]);          // self loop
        int2 r = rowp2[n];
        int e = r.x, e1 = r.y;
        while (e < e1 && (e & 3)){ addrow8(acc, tv[(size_t)esrc[e]*4 + l]); e++; }
        for (; e + 7 < e1; e += 8){
            int4 a4 = nt_load_i4(&esrc[e]);
            int4 b4 = nt_load_i4(&esrc[e+4]);
            float4 v0 = tv[(size_t)a4.x*4 + l];
            float4 v1 = tv[(size_t)a4.y*4 + l];
            float4 v2 = tv[(size_t)a4.z*4 + l];
            float4 v3 = tv[(size_t)a4.w*4 + l];
            float4 v4 = tv[(size_t)b4.x*4 + l];
            float4 v5 = tv[(size_t)b4.y*4 + l];
            float4 v6 = tv[(size_t)b4.z*4 + l];
            float4 v7 = tv[(size_t)b4.w*4 + l];
            addrow8(acc, h2add4f(h2add4f(v0, v1), h2add4f(v2, v3)));
            addrow8(acc, h2add4f(h2add4f(v4, v5), h2add4f(v6, v7)));
        }
        for (; e + 3 < e1; e += 4){
            int4 s4 = nt_load_i4(&esrc[e]);
            float4 v0 = tv[(size_t)s4.x*4 + l];
            float4 v1 = tv[(size_t)s4.y*4 + l];
            float4 v2 = tv[(size_t)s4.z*4 + l];
            float4 v3 = tv[(size_t)s4.w*4 + l];
            addrow8(acc, h2add4f(h2add4f(v0, v1), h2add4f(v2, v3)));
        }
        for (; e < e1; e++) addrow8(acc, tv[(size_t)esrc[e]*4 + l]);
        d = dis[n];
#pragma unroll
        for (int c = 0; c < 8; c++)
            acc[c] = elu1(fmaf(d, acc[c], bias[8*l + c]));
    }
    __syncthreads();
#pragma unroll
    for (int c = 0; c < 8; c++) sh[nib][8*l + c] = acc[c];
    __syncthreads();
    float o[8] = {0.f,0.f,0.f,0.f,0.f,0.f,0.f,0.f};
#pragma unroll
    for (int i = 0; i < HF; i++){
        float hvv = sh[nib][i];
        float4 w0 = *(const float4*)&sW[i*HF + 8*l];
        float4 w1 = *(const float4*)&sW[i*HF + 8*l + 4];
        o[0] = fmaf(hvv, w0.x, o[0]); o[1] = fmaf(hvv, w0.y, o[1]);
        o[2] = fmaf(hvv, w0.z, o[2]); o[3] = fmaf(hvv, w0.w, o[3]);
        o[4] = fmaf(hvv, w1.x, o[4]); o[5] = fmaf(hvv, w1.y, o[5]);
        o[6] = fmaf(hvv, w1.z, o[6]); o[7] = fmaf(hvv, w1.w, o[7]);
    }
    if (n >= 0){
        __half2 hh[4];
#pragma unroll
        for (int k = 0; k < 4; k++)
            hh[k] = __float22half2_rn(make_float2(o[2*k]*d, o[2*k+1]*d));
        ((float4*)tout)[(size_t)n*4 + l] = *(float4*)hh;
    }
}

// ------- final: gather layer3 + elu, output MLP + sigmoid col 0 -------------
__global__ __launch_bounds__(256)
void k_gather_out(const __half* __restrict__ tin, const int* __restrict__ esrc,
                  const int2* __restrict__ rowp2, const float* __restrict__ dis,
                  const int* __restrict__ norder,
                  const float* __restrict__ bg3,
                  const float* __restrict__ wo1, const float* __restrict__ bo1,
                  const float* __restrict__ wo2, const float* __restrict__ bo2,
                  const float* __restrict__ wo3, const float* __restrict__ bo3,
                  float* __restrict__ out, int N){
    __shared__ float sW1[HF*HF], sW2[HF*HF], sW3[HF*4];
    __shared__ float sh[64][33], sh2[64][33];
    int tid = threadIdx.x;
    for (int i = tid; i < HF*HF; i += 256){ sW1[i] = wo1[i]; sW2[i] = wo2[i]; }
    if (tid < HF*4) sW3[tid] = wo3[tid];
    int nib = tid >> 2, l = tid & 3;
    int n = norder[blockIdx.x*64 + nib];
    float acc[8] = {0.f,0.f,0.f,0.f,0.f,0.f,0.f,0.f};
    const float4* tv = (const float4*)tin;
    if (n >= 0){
        addrow8(acc, tv[(size_t)n*4 + l]);
        int2 r = rowp2[n];
        int e = r.x, e1 = r.y;
        while (e < e1 && (e & 3)){ addrow8(acc, tv[(size_t)esrc[e]*4 + l]); e++; }
        for (; e + 7 < e1; e += 8){
            int4 a4 = nt_load_i4(&esrc[e]);
            int4 b4 = nt_load_i4(&esrc[e+4]);
            float4 v0 = tv[(size_t)a4.x*4 + l];
            float4 v1 = tv[(size_t)a4.y*4 + l];
            float4 v2 = tv[(size_t)a4.z*4 + l];
            float4 v3 = tv[(size_t)a4.w*4 + l];
            float4 v4 = tv[(size_t)b4.x*4 + l];
            float4 v5 = tv[(size_t)b4.y*4 + l];
            float4 v6 = tv[(size_t)b4.z*4 + l];
            float4 v7 = tv[(size_t)b4.w*4 + l];
            addrow8(acc, h2add4f(h2add4f(v0, v1), h2add4f(v2, v3)));
            addrow8(acc, h2add4f(h2add4f(v4, v5), h2add4f(v6, v7)));
        }
        for (; e + 3 < e1; e += 4){
            int4 s4 = nt_load_i4(&esrc[e]);
            float4 v0 = tv[(size_t)s4.x*4 + l];
            float4 v1 = tv[(size_t)s4.y*4 + l];
            float4 v2 = tv[(size_t)s4.z*4 + l];
            float4 v3 = tv[(size_t)s4.w*4 + l];
            addrow8(acc, h2add4f(h2add4f(v0, v1), h2add4f(v2, v3)));
        }
        for (; e < e1; e++) addrow8(acc, tv[(size_t)esrc[e]*4 + l]);
        float d = dis[n];
#pragma unroll
        for (int c = 0; c < 8; c++)
            acc[c] = elu1(fmaf(d, acc[c], bg3[8*l + c]));
    }
    __syncthreads();
#pragma unroll
    for (int c = 0; c < 8; c++) sh[nib][8*l + c] = acc[c];
    __syncthreads();
    float o1[8];
#pragma unroll
    for (int c = 0; c < 8; c++) o1[c] = bo1[8*l + c];
#pragma unroll
    for (int i = 0; i < HF; i++){
        float hvv = sh[nib][i];
        float4 w0 = *(const float4*)&sW1[i*HF + 8*l];
        float4 w1 = *(const float4*)&sW1[i*HF + 8*l + 4];
        o1[0] = fmaf(hvv, w0.x, o1[0]); o1[1] = fmaf(hvv, w0.y, o1[1]);
        o1[2] = fmaf(hvv, w0.z, o1[2]); o1[3] = fmaf(hvv, w0.w, o1[3]);
        o1[4] = fmaf(hvv, w1.x, o1[4]); o1[5] = fmaf(hvv, w1.y, o1[5]);
        o1[6] = fmaf(hvv, w1.z, o1[6]); o1[7] = fmaf(hvv, w1.w, o1[7]);
    }
#pragma unroll
    for (int c = 0; c < 8; c++) sh2[nib][8*l + c] = leaky(o1[c]);
    __syncthreads();
    float o2[8];
#pragma unroll
    for (int c = 0; c < 8; c++) o2[c] = bo2[8*l + c];
#pragma unroll
    for (int i = 0; i < HF; i++){
        float hvv = sh2[nib][i];
        float4 w0 = *(const float4*)&sW2[i*HF + 8*l];
        float4 w1 = *(const float4*)&sW2[i*HF + 8*l + 4];
        o2[0] = fmaf(hvv, w0.x, o2[0]); o2[1] = fmaf(hvv, w0.y, o2[1]);
        o2[2] = fmaf(hvv, w0.z, o2[2]); o2[3] = fmaf(hvv, w0.w, o2[3]);
        o2[4] = fmaf(hvv, w1.x, o2[4]); o2[5] = fmaf(hvv, w1.y, o2[5]);
        o2[6] = fmaf(hvv, w1.z, o2[6]); o2[7] = fmaf(hvv, w1.w, o2[7]);
    }
#pragma unroll
    for (int c = 0; c < 8; c++) sh[nib][8*l + c] = leaky(o2[c]);
    __syncthreads();
    if (n >= 0){
        float v = bo3[l];
#pragma unroll
        for (int i = 0; i < HF; i++) v = fmaf(sh[nib][i], sW3[i*4 + l], v);
        if (l == 0) v = sigmoidf(v);
        out[(size_t)n*4 + l] = v;
    }
}

extern "C" void kernel_launch(void* const* d_in, const int* in_sizes, int n_in,
                              void* d_out, int out_size, void* d_ws, size_t ws_size,
                              hipStream_t stream) {
    const float* x     = (const float*)d_in[0];
    const float* w_in1 = (const float*)d_in[1];
    const float* b_in1 = (const float*)d_in[2];
    const float* w_in2 = (const float*)d_in[3];
    const float* b_in2 = (const float*)d_in[4];
    const float* gamma = (const float*)d_in[5];
    const float* beta  = (const float*)d_in[6];
    const float* wg1   = (const float*)d_in[7];
    const float* bg1   = (const float*)d_in[8];
    const float* wg2   = (const float*)d_in[9];
    const float* bg2   = (const float*)d_in[10];
    const float* wg3   = (const float*)d_in[11];
    const float* bg3   = (const float*)d_in[12];
    const float* wo1   = (const float*)d_in[13];
    const float* bo1   = (const float*)d_in[14];
    const float* wo2   = (const float*)d_in[15];
    const float* bo2   = (const float*)d_in[16];
    const float* wo3   = (const float*)d_in[17];
    const float* bo3   = (const float*)d_in[18];
    const int*   ei    = (const int*)d_in[19];

    int N = in_sizes[0] / 3;
    int E = in_sizes[19] / 2;
    int B = (N + BSZ - 1) >> BSH;          // buckets (782; lcnt arrays hold 1024)

    char* w = (char*)d_ws;
    size_t o = 0;
    auto alloc = [&](size_t bytes){ size_t r = o; o = (o + bytes + 255) & ~(size_t)255; return r; };
    // ---- zeroed region ----
    float* stats = (float*)(w + alloc(2*HF*sizeof(float)));
    int*   gfill = (int*)  (w + alloc((size_t)B*8*4));
    int*   deg   = (int*)  (w + alloc((size_t)N*4));
    size_t zero_bytes = o;
    // ---- rest ----
    int2*  rowp2 = (int2*) (w + alloc((size_t)N*8));
    float* dis   = (float*)(w + alloc((size_t)N*4));
    int*   norder= (int*)  (w + alloc((size_t)B*BSZ*4));
    int*   ep    = (int*)  (w + alloc((size_t)B*CAP*4));
    __half* bufH = (__half*)(w + alloc((size_t)N*HF*2));
    __half* tA   = (__half*)(w + alloc((size_t)N*HF*2));
    __half* tB   = (__half*)(w + alloc((size_t)N*HF*2));

    hipMemsetAsync(d_ws, 0, zero_bytes, stream);

    const int* src = ei;
    const int* dst = ei + E;
    int NB1 = (N + 255) / 256;
    int NC  = (E + CH - 1) / CH;
    int GBT = (N + 63) / 64;
    int NS  = 2*B;                         // B*128/64 slots for gathers

    k_mlp_bin<<<NC + NB1, 256, 0, stream>>>(x, w_in1, b_in1, w_in2, b_in2, bufH, stats,
                                            src, dst, gfill, ep, deg, N, E, B, NC);
    k_csr_bn<<<B + GBT, 256, 0, stream>>>(ep, gfill, deg, rowp2, dis, norder,
                                          bufH, stats, gamma, beta, wg1, tA, N, B);
    k_gather_t<<<NS, 256, 0, stream>>>(tA, ep, rowp2, dis, norder, bg1, wg2, tB, N);
    k_gather_t<<<NS, 256, 0, stream>>>(tB, ep, rowp2, dis, norder, bg2, wg3, tA, N);
    k_gather_out<<<NS, 256, 0, stream>>>(tA, ep, rowp2, dis, norder, bg3,
                                         wo1, bo1, wo2, bo2, wo3, bo3, (float*)d_out, N);
}

// Round 2
// 307.372 us; speedup vs baseline: 1.2438x; 1.2438x over previous
//
#include <hip/hip_runtime.h>
#include <hip/hip_fp16.h>

#define HF 32
#define EPS 1e-5f
#define BSH 7
#define BSZ 128          // nodes per bucket
#define CH  4096         // edges per binning block (single-pass, fits in regs)
#define SUBCAP 512       // per-XCD sub-segment capacity
#define CAP (8*SUBCAP)   // bucket segment capacity (4096)

typedef int vi4 __attribute__((ext_vector_type(4)));

__device__ __forceinline__ float leaky(float v){ return fmaxf(v, 0.01f*v); }
__device__ __forceinline__ float elu1(float v){ return v > 0.f ? v : (expf(v)-1.f); }
__device__ __forceinline__ float sigmoidf(float v){ return 1.f/(1.f+expf(-v)); }

// nt 16B index load (read-once stream). NOTE: nt LOADS only — nt stores on
// scattered writes caused 143MB HBM writeback (round 10); scattered global
// ATOMICS caused +84MB writeback (round 1). Keep all scatter traffic plain,
// and keep per-node reductions in LDS.
__device__ __forceinline__ int4 nt_load_i4(const int* p){
    vi4 v = __builtin_nontemporal_load((const vi4*)p);
    return make_int4(v.x, v.y, v.z, v.w);
}

// add 8 halfs (16B) into fp32 accumulator
__device__ __forceinline__ void addrow8(float* a, float4 v){
    const __half2* p = (const __half2*)&v;
#pragma unroll
    for (int k = 0; k < 4; k++){
        float2 f = __half22float2(p[k]);
        a[2*k] += f.x; a[2*k+1] += f.y;
    }
}
// packed fp16 add of two 8-half rows
__device__ __forceinline__ float4 h2add4f(float4 a, float4 b){
    __half2* pa = (__half2*)&a; __half2* pb = (__half2*)&b;
    float4 r; __half2* pr = (__half2*)&r;
#pragma unroll
    for (int k = 0; k < 4; k++) pr[k] = __hadd2(pa[k], pb[k]);
    return r;
}

// ===== fused: edge binning (single pass from regs) | input MLP + BN stats ===
// bin blocks FIRST in the grid so their latency overlaps MLP compute.
union SMem {
    struct {
        float sW1[3*HF]; float sB1[HF]; float sW2[HF*HF]; float sB2[HF];
        float sh[256][33];
    } mlp;
    struct { int lcnt[1024]; int lbase[1024]; int lpos[1024]; } bin;
};

__global__ __launch_bounds__(256)
void k_mlp_bin(const float* __restrict__ x,
               const float* __restrict__ w1, const float* __restrict__ b1,
               const float* __restrict__ w2, const float* __restrict__ b2,
               __half* __restrict__ h, float* __restrict__ stats,
               const int* __restrict__ src, const int* __restrict__ dst,
               int* __restrict__ gfill, int* __restrict__ ep,
               int N, int E, int B, int NC){
    __shared__ SMem sm;
    int t = threadIdx.x;
    if ((int)blockIdx.x < NC){
        // ---------------- binning: single pass, chunk held in regs --------
        int bid = blockIdx.x;
        for (int i = t; i < B; i += 256){ sm.bin.lcnt[i] = 0; sm.bin.lpos[i] = 0; }
        __syncthreads();
        int base = bid * CH;
        int xcd = bid & 7;
        int dv[16], sv[16];
        if (base + CH <= E){
#pragma unroll
            for (int i = 0; i < 4; i++){
                int4 d4 = nt_load_i4(dst + base + (t + i*256)*4);
                int4 s4 = nt_load_i4(src + base + (t + i*256)*4);
                dv[4*i]   = d4.x; dv[4*i+1] = d4.y; dv[4*i+2] = d4.z; dv[4*i+3] = d4.w;
                sv[4*i]   = s4.x; sv[4*i+1] = s4.y; sv[4*i+2] = s4.z; sv[4*i+3] = s4.w;
            }
        } else {
#pragma unroll
            for (int i = 0; i < 16; i++){
                int e = base + t + i*256;
                dv[i] = (e < E) ? dst[e] : -1;
                sv[i] = (e < E) ? src[e] : 0;
            }
        }
#pragma unroll
        for (int i = 0; i < 16; i++)
            if (dv[i] >= 0) atomicAdd(&sm.bin.lcnt[dv[i] >> BSH], 1);
        __syncthreads();
        // reserve contiguous range in this block's xcd sub-segment per bucket
        for (int i = t; i < B; i += 256){
            int c = sm.bin.lcnt[i];
            sm.bin.lbase[i] = c ? (i*CAP + xcd*SUBCAP + atomicAdd(&gfill[i*8 + xcd], c)) : 0;
        }
        __syncthreads();
        // scatter straight from registers (no re-read)
#pragma unroll
        for (int i = 0; i < 16; i++)
            if (dv[i] >= 0){
                int bb = dv[i] >> BSH;
                int p = sm.bin.lbase[bb] + atomicAdd(&sm.bin.lpos[bb], 1);
                ep[p] = (sv[i] << BSH) | (dv[i] & (BSZ-1));
            }
    } else {
        // ---------------- MLP + BN stats ----------------
        for (int i = t; i < 3*HF; i += 256) sm.mlp.sW1[i] = w1[i];
        if (t < HF){ sm.mlp.sB1[t] = b1[t]; sm.mlp.sB2[t] = b2[t]; }
        for (int i = t; i < HF*HF; i += 256) sm.mlp.sW2[i] = w2[i];
        __syncthreads();
        int n = (blockIdx.x - NC)*256 + t;
        float h2[HF];
        if (n < N){
            float x0 = x[(size_t)n*3], x1 = x[(size_t)n*3+1], x2 = x[(size_t)n*3+2];
            float h1[HF];
#pragma unroll
            for (int j = 0; j < HF; j++){
                float v = fmaf(x0, sm.mlp.sW1[j], fmaf(x1, sm.mlp.sW1[HF+j],
                          fmaf(x2, sm.mlp.sW1[2*HF+j], sm.mlp.sB1[j])));
                h1[j] = leaky(v);
            }
#pragma unroll
            for (int j = 0; j < HF; j++){
                float v = sm.mlp.sB2[j];
#pragma unroll
                for (int i = 0; i < HF; i++) v = fmaf(h1[i], sm.mlp.sW2[i*HF+j], v);
                h2[j] = leaky(v);
            }
            float4* hv = (float4*)(h + (size_t)n*HF);
#pragma unroll
            for (int jb = 0; jb < 4; jb++){
                __half2 hh[4];
#pragma unroll
                for (int k = 0; k < 4; k++)
                    hh[k] = __float22half2_rn(make_float2(h2[jb*8+2*k], h2[jb*8+2*k+1]));
                hv[jb] = *(float4*)hh;
            }
        } else {
#pragma unroll
            for (int j = 0; j < HF; j++) h2[j] = 0.f;
        }
#pragma unroll
        for (int j = 0; j < HF; j++) sm.mlp.sh[t][j] = h2[j];
        __syncthreads();
        int f = t & 31, g = t >> 5;
        float s = 0.f, ss = 0.f;
        for (int i = 0; i < 32; i++){
            float v = sm.mlp.sh[g*32 + i][f];
            s += v; ss += v*v;
        }
        __syncthreads();
        sm.mlp.sh[g][f] = s; sm.mlp.sh[8+g][f] = ss;
        __syncthreads();
        if (t < HF){
            float a = 0.f, b = 0.f;
#pragma unroll
            for (int g2 = 0; g2 < 8; g2++){ a += sm.mlp.sh[g2][t]; b += sm.mlp.sh[8+g2][t]; }
            atomicAdd(&stats[t], a);
            atomicAdd(&stats[HF+t], b);
        }
    }
}

// ===== fused per-bucket: CSR build + degree-sort + BN + t1 =================
// One block per bucket. lcnt[t] (LDS count over the bucket's own edges) IS
// deg[n] for n = b*128+t — no global deg array, no global atomics.
// After the scatter, threads t<128 run BN + (h@W1)*dis for their own node
// entirely from registers (W1 + BN scale/shift staged in LDS).
__global__ __launch_bounds__(256)
void k_csr_t1(int* __restrict__ ep, const int* __restrict__ gfill,
              int2* __restrict__ rowp2, float* __restrict__ dis,
              int* __restrict__ norder,
              const __half* __restrict__ h, const float* __restrict__ stats,
              const float* __restrict__ gamma, const float* __restrict__ beta,
              const float* __restrict__ W, __half* __restrict__ tout,
              int N, int B){
    __shared__ int sep[CAP];
    __shared__ int lcnt[128], lpre[128], lfill[128];
    __shared__ float sW[HF*HF];
    __shared__ float sscale[HF], sshift[HF];
    int t = threadIdx.x;
    int b = blockIdx.x;
    for (int i = t; i < HF*HF; i += 256) sW[i] = W[i];
    if (t < HF){
        float inv = 1.0f/(float)N;
        float mu  = stats[t]*inv;
        float var = stats[HF+t]*inv - mu*mu;
        float rs  = rsqrtf(var + EPS);
        float sc  = rs*gamma[t];
        sscale[t] = sc;
        sshift[t] = beta[t] - mu*sc;
    }
    if (t < 128){ lcnt[t] = 0; lfill[t] = 0; }
    int cx[8], coff[8], cnt = 0;
#pragma unroll
    for (int xx = 0; xx < 8; xx++){ cx[xx] = gfill[b*8 + xx]; coff[xx] = cnt; cnt += cx[xx]; }
    int base = b*CAP;
    __syncthreads();
#pragma unroll
    for (int xx = 0; xx < 8; xx++)
        for (int j = t; j < cx[xx]; j += 256) sep[coff[xx] + j] = ep[base + xx*SUBCAP + j];
    __syncthreads();
    for (int e = t; e < cnt; e += 256) atomicAdd(&lcnt[sep[e] & (BSZ-1)], 1);
    __syncthreads();
    int dg = 0; float dloc = 0.f; int n = b*BSZ + t;
    if (t < 128){
        dg = lcnt[t];
        int pre = 0, rank = 0;
        for (int j = 0; j < 128; j++){
            int dj = lcnt[j];                          // LDS broadcast
            if (j < t) pre += dj;
            if (dj > dg || (dj == dg && j < t)) rank++;
        }
        lpre[t] = pre;
        if (n < N){
            rowp2[n] = make_int2(base + pre, base + pre + dg);
            dloc = rsqrtf((float)dg + 1.0f);
            dis[n] = dloc;
            norder[b*BSZ + rank] = n;                  // degree-descending order
        } else {
            norder[b*BSZ + rank] = -1;                 // invalid slots sort last
        }
    }
    __syncthreads();
    for (int e = t; e < cnt; e += 256){
        int val = sep[e];
        int d = val & (BSZ-1);
        int p = lpre[d] + atomicAdd(&lfill[d], 1);
        ep[base + p] = val >> BSH;                     // strip -> plain src index
    }
    // ---------------- BN + t1 for this bucket's nodes (t<128) --------------
    if (t < 128 && n < N){
        const float4* hv4 = (const float4*)h + (size_t)n*4;
        float v[HF];
#pragma unroll
        for (int k = 0; k < 4; k++){
            float4 raw = hv4[k];
            const __half2* p2 = (const __half2*)&raw;
#pragma unroll
            for (int q = 0; q < 4; q++){
                float2 f2 = __half22float2(p2[q]);
                v[8*k + 2*q]     = f2.x;
                v[8*k + 2*q + 1] = f2.y;
            }
        }
#pragma unroll
        for (int f = 0; f < HF; f++) v[f] = fmaf(v[f], sscale[f], sshift[f]);
        float o[HF];
#pragma unroll
        for (int j = 0; j < HF; j++) o[j] = 0.f;
#pragma unroll
        for (int i = 0; i < HF; i++){
            float vi = v[i];
#pragma unroll
            for (int j4 = 0; j4 < 8; j4++){
                float4 w4 = *(const float4*)&sW[i*HF + 4*j4];
                o[4*j4]   = fmaf(vi, w4.x, o[4*j4]);
                o[4*j4+1] = fmaf(vi, w4.y, o[4*j4+1]);
                o[4*j4+2] = fmaf(vi, w4.z, o[4*j4+2]);
                o[4*j4+3] = fmaf(vi, w4.w, o[4*j4+3]);
            }
        }
        float4* ov = (float4*)tout + (size_t)n*4;
#pragma unroll
        for (int k = 0; k < 4; k++){
            __half2 hh[4];
#pragma unroll
            for (int q = 0; q < 4; q++)
                hh[q] = __float22half2_rn(make_float2(o[8*k+2*q]*dloc, o[8*k+2*q+1]*dloc));
            ov[k] = *(float4*)hh;
        }
    }
}

// ------- per-node gather (degree-sorted order, 8-deep row loads) ------------
__global__ __launch_bounds__(256)
void k_gather_t(const __half* __restrict__ tin, const int* __restrict__ esrc,
                const int2* __restrict__ rowp2, const float* __restrict__ dis,
                const int* __restrict__ norder,
                const float* __restrict__ bias, const float* __restrict__ W,
                __half* __restrict__ tout, int N){
    __shared__ float sW[HF*HF];
    __shared__ float sh[64][33];
    int tid = threadIdx.x;
    for (int i = tid; i < HF*HF; i += 256) sW[i] = W[i];
    int nib = tid >> 2, l = tid & 3;
    int n = norder[blockIdx.x*64 + nib];
    float acc[8] = {0.f,0.f,0.f,0.f,0.f,0.f,0.f,0.f};
    float d = 0.f;
    const float4* tv = (const float4*)tin;
    if (n >= 0){
        addrow8(acc, tv[(size_t)n*4 + l]);          // self loop
        int2 r = rowp2[n];
        int e = r.x, e1 = r.y;
        while (e < e1 && (e & 3)){ addrow8(acc, tv[(size_t)esrc[e]*4 + l]); e++; }
        for (; e + 7 < e1; e += 8){
            int4 a4 = nt_load_i4(&esrc[e]);
            int4 b4 = nt_load_i4(&esrc[e+4]);
            float4 v0 = tv[(size_t)a4.x*4 + l];
            float4 v1 = tv[(size_t)a4.y*4 + l];
            float4 v2 = tv[(size_t)a4.z*4 + l];
            float4 v3 = tv[(size_t)a4.w*4 + l];
            float4 v4 = tv[(size_t)b4.x*4 + l];
            float4 v5 = tv[(size_t)b4.y*4 + l];
            float4 v6 = tv[(size_t)b4.z*4 + l];
            float4 v7 = tv[(size_t)b4.w*4 + l];
            addrow8(acc, h2add4f(h2add4f(v0, v1), h2add4f(v2, v3)));
            addrow8(acc, h2add4f(h2add4f(v4, v5), h2add4f(v6, v7)));
        }
        for (; e + 3 < e1; e += 4){
            int4 s4 = nt_load_i4(&esrc[e]);
            float4 v0 = tv[(size_t)s4.x*4 + l];
            float4 v1 = tv[(size_t)s4.y*4 + l];
            float4 v2 = tv[(size_t)s4.z*4 + l];
            float4 v3 = tv[(size_t)s4.w*4 + l];
            addrow8(acc, h2add4f(h2add4f(v0, v1), h2add4f(v2, v3)));
        }
        for (; e < e1; e++) addrow8(acc, tv[(size_t)esrc[e]*4 + l]);
        d = dis[n];
#pragma unroll
        for (int c = 0; c < 8; c++)
            acc[c] = elu1(fmaf(d, acc[c], bias[8*l + c]));
    }
    __syncthreads();
#pragma unroll
    for (int c = 0; c < 8; c++) sh[nib][8*l + c] = acc[c];
    __syncthreads();
    float o[8] = {0.f,0.f,0.f,0.f,0.f,0.f,0.f,0.f};
#pragma unroll
    for (int i = 0; i < HF; i++){
        float hvv = sh[nib][i];
        float4 w0 = *(const float4*)&sW[i*HF + 8*l];
        float4 w1 = *(const float4*)&sW[i*HF + 8*l + 4];
        o[0] = fmaf(hvv, w0.x, o[0]); o[1] = fmaf(hvv, w0.y, o[1]);
        o[2] = fmaf(hvv, w0.z, o[2]); o[3] = fmaf(hvv, w0.w, o[3]);
        o[4] = fmaf(hvv, w1.x, o[4]); o[5] = fmaf(hvv, w1.y, o[5]);
        o[6] = fmaf(hvv, w1.z, o[6]); o[7] = fmaf(hvv, w1.w, o[7]);
    }
    if (n >= 0){
        __half2 hh[4];
#pragma unroll
        for (int k = 0; k < 4; k++)
            hh[k] = __float22half2_rn(make_float2(o[2*k]*d, o[2*k+1]*d));
        ((float4*)tout)[(size_t)n*4 + l] = *(float4*)hh;
    }
}

// ------- final: gather layer3 + elu, output MLP + sigmoid col 0 -------------
__global__ __launch_bounds__(256)
void k_gather_out(const __half* __restrict__ tin, const int* __restrict__ esrc,
                  const int2* __restrict__ rowp2, const float* __restrict__ dis,
                  const int* __restrict__ norder,
                  const float* __restrict__ bg3,
                  const float* __restrict__ wo1, const float* __restrict__ bo1,
                  const float* __restrict__ wo2, const float* __restrict__ bo2,
                  const float* __restrict__ wo3, const float* __restrict__ bo3,
                  float* __restrict__ out, int N){
    __shared__ float sW1[HF*HF], sW2[HF*HF], sW3[HF*4];
    __shared__ float sh[64][33], sh2[64][33];
    int tid = threadIdx.x;
    for (int i = tid; i < HF*HF; i += 256){ sW1[i] = wo1[i]; sW2[i] = wo2[i]; }
    if (tid < HF*4) sW3[tid] = wo3[tid];
    int nib = tid >> 2, l = tid & 3;
    int n = norder[blockIdx.x*64 + nib];
    float acc[8] = {0.f,0.f,0.f,0.f,0.f,0.f,0.f,0.f};
    const float4* tv = (const float4*)tin;
    if (n >= 0){
        addrow8(acc, tv[(size_t)n*4 + l]);
        int2 r = rowp2[n];
        int e = r.x, e1 = r.y;
        while (e < e1 && (e & 3)){ addrow8(acc, tv[(size_t)esrc[e]*4 + l]); e++; }
        for (; e + 7 < e1; e += 8){
            int4 a4 = nt_load_i4(&esrc[e]);
            int4 b4 = nt_load_i4(&esrc[e+4]);
            float4 v0 = tv[(size_t)a4.x*4 + l];
            float4 v1 = tv[(size_t)a4.y*4 + l];
            float4 v2 = tv[(size_t)a4.z*4 + l];
            float4 v3 = tv[(size_t)a4.w*4 + l];
            float4 v4 = tv[(size_t)b4.x*4 + l];
            float4 v5 = tv[(size_t)b4.y*4 + l];
            float4 v6 = tv[(size_t)b4.z*4 + l];
            float4 v7 = tv[(size_t)b4.w*4 + l];
            addrow8(acc, h2add4f(h2add4f(v0, v1), h2add4f(v2, v3)));
            addrow8(acc, h2add4f(h2add4f(v4, v5), h2add4f(v6, v7)));
        }
        for (; e + 3 < e1; e += 4){
            int4 s4 = nt_load_i4(&esrc[e]);
            float4 v0 = tv[(size_t)s4.x*4 + l];
            float4 v1 = tv[(size_t)s4.y*4 + l];
            float4 v2 = tv[(size_t)s4.z*4 + l];
            float4 v3 = tv[(size_t)s4.w*4 + l];
            addrow8(acc, h2add4f(h2add4f(v0, v1), h2add4f(v2, v3)));
        }
        for (; e < e1; e++) addrow8(acc, tv[(size_t)esrc[e]*4 + l]);
        float d = dis[n];
#pragma unroll
        for (int c = 0; c < 8; c++)
            acc[c] = elu1(fmaf(d, acc[c], bg3[8*l + c]));
    }
    __syncthreads();
#pragma unroll
    for (int c = 0; c < 8; c++) sh[nib][8*l + c] = acc[c];
    __syncthreads();
    float o1[8];
#pragma unroll
    for (int c = 0; c < 8; c++) o1[c] = bo1[8*l + c];
#pragma unroll
    for (int i = 0; i < HF; i++){
        float hvv = sh[nib][i];
        float4 w0 = *(const float4*)&sW1[i*HF + 8*l];
        float4 w1 = *(const float4*)&sW1[i*HF + 8*l + 4];
        o1[0] = fmaf(hvv, w0.x, o1[0]); o1[1] = fmaf(hvv, w0.y, o1[1]);
        o1[2] = fmaf(hvv, w0.z, o1[2]); o1[3] = fmaf(hvv, w0.w, o1[3]);
        o1[4] = fmaf(hvv, w1.x, o1[4]); o1[5] = fmaf(hvv, w1.y, o1[5]);
        o1[6] = fmaf(hvv, w1.z, o1[6]); o1[7] = fmaf(hvv, w1.w, o1[7]);
    }
#pragma unroll
    for (int c = 0; c < 8; c++) sh2[nib][8*l + c] = leaky(o1[c]);
    __syncthreads();
    float o2[8];
#pragma unroll
    for (int c = 0; c < 8; c++) o2[c] = bo2[8*l + c];
#pragma unroll
    for (int i = 0; i < HF; i++){
        float hvv = sh2[nib][i];
        float4 w0 = *(const float4*)&sW2[i*HF + 8*l];
        float4 w1 = *(const float4*)&sW2[i*HF + 8*l + 4];
        o2[0] = fmaf(hvv, w0.x, o2[0]); o2[1] = fmaf(hvv, w0.y, o2[1]);
        o2[2] = fmaf(hvv, w0.z, o2[2]); o2[3] = fmaf(hvv, w0.w, o2[3]);
        o2[4] = fmaf(hvv, w1.x, o2[4]); o2[5] = fmaf(hvv, w1.y, o2[5]);
        o2[6] = fmaf(hvv, w1.z, o2[6]); o2[7] = fmaf(hvv, w1.w, o2[7]);
    }
#pragma unroll
    for (int c = 0; c < 8; c++) sh[nib][8*l + c] = leaky(o2[c]);
    __syncthreads();
    if (n >= 0){
        float v = bo3[l];
#pragma unroll
        for (int i = 0; i < HF; i++) v = fmaf(sh[nib][i], sW3[i*4 + l], v);
        if (l == 0) v = sigmoidf(v);
        out[(size_t)n*4 + l] = v;
    }
}

extern "C" void kernel_launch(void* const* d_in, const int* in_sizes, int n_in,
                              void* d_out, int out_size, void* d_ws, size_t ws_size,
                              hipStream_t stream) {
    const float* x     = (const float*)d_in[0];
    const float* w_in1 = (const float*)d_in[1];
    const float* b_in1 = (const float*)d_in[2];
    const float* w_in2 = (const float*)d_in[3];
    const float* b_in2 = (const float*)d_in[4];
    const float* gamma = (const float*)d_in[5];
    const float* beta  = (const float*)d_in[6];
    const float* wg1   = (const float*)d_in[7];
    const float* bg1   = (const float*)d_in[8];
    const float* wg2   = (const float*)d_in[9];
    const float* bg2   = (const float*)d_in[10];
    const float* wg3   = (const float*)d_in[11];
    const float* bg3   = (const float*)d_in[12];
    const float* wo1   = (const float*)d_in[13];
    const float* bo1   = (const float*)d_in[14];
    const float* wo2   = (const float*)d_in[15];
    const float* bo2   = (const float*)d_in[16];
    const float* wo3   = (const float*)d_in[17];
    const float* bo3   = (const float*)d_in[18];
    const int*   ei    = (const int*)d_in[19];

    int N = in_sizes[0] / 3;
    int E = in_sizes[19] / 2;
    int B = (N + BSZ - 1) >> BSH;          // buckets (782; lcnt arrays hold 1024)

    char* w = (char*)d_ws;
    size_t o = 0;
    auto alloc = [&](size_t bytes){ size_t r = o; o = (o + bytes + 255) & ~(size_t)255; return r; };
    // ---- zeroed region ----
    float* stats = (float*)(w + alloc(2*HF*sizeof(float)));
    int*   gfill = (int*)  (w + alloc((size_t)B*8*4));
    size_t zero_bytes = o;
    // ---- rest ----
    int2*  rowp2 = (int2*) (w + alloc((size_t)N*8));
    float* dis   = (float*)(w + alloc((size_t)N*4));
    int*   norder= (int*)  (w + alloc((size_t)B*BSZ*4));
    int*   ep    = (int*)  (w + alloc((size_t)B*CAP*4));
    __half* bufH = (__half*)(w + alloc((size_t)N*HF*2));
    __half* tA   = (__half*)(w + alloc((size_t)N*HF*2));
    __half* tB   = (__half*)(w + alloc((size_t)N*HF*2));

    hipMemsetAsync(d_ws, 0, zero_bytes, stream);

    const int* src = ei;
    const int* dst = ei + E;
    int NB1 = (N + 255) / 256;
    int NC  = (E + CH - 1) / CH;
    int NS  = 2*B;                         // B*128/64 slots for gathers

    k_mlp_bin<<<NC + NB1, 256, 0, stream>>>(x, w_in1, b_in1, w_in2, b_in2, bufH, stats,
                                            src, dst, gfill, ep, N, E, B, NC);
    k_csr_t1<<<B, 256, 0, stream>>>(ep, gfill, rowp2, dis, norder,
                                    bufH, stats, gamma, beta, wg1, tA, N, B);
    k_gather_t<<<NS, 256, 0, stream>>>(tA, ep, rowp2, dis, norder, bg1, wg2, tB, N);
    k_gather_t<<<NS, 256, 0, stream>>>(tB, ep, rowp2, dis, norder, bg2, wg3, tA, N);
    k_gather_out<<<NS, 256, 0, stream>>>(tA, ep, rowp2, dis, norder, bg3,
                                         wo1, bo1, wo2, bo2, wo3, bo3, (float*)d_out, N);
}

// Round 3
// 286.375 us; speedup vs baseline: 1.3349x; 1.0733x over previous
//
#include <hip/hip_runtime.h>
#include <hip/hip_fp16.h>

#define HF 32
#define EPS 1e-5f
#define BSH 7
#define BSZ 128          // nodes per bucket
#define CH  4096         // edges per binning block (single-pass, fits in regs)
#define SUBCAP 512       // per-XCD sub-segment capacity
#define CAP (8*SUBCAP)   // bucket segment capacity (4096)

typedef int vi4 __attribute__((ext_vector_type(4)));

__device__ __forceinline__ float leaky(float v){ return fmaxf(v, 0.01f*v); }
__device__ __forceinline__ float elu1(float v){ return v > 0.f ? v : (expf(v)-1.f); }
__device__ __forceinline__ float sigmoidf(float v){ return 1.f/(1.f+expf(-v)); }

// nt 16B index load (read-once stream). NOTE: nt LOADS only — nt stores on
// scattered writes caused 143MB HBM writeback (round 10); scattered global
// ATOMICS caused +84MB writeback (round 1). Degree-sorting node order caused
// inter-block imbalance + locality loss (round 2). Natural order, plain
// stores, LDS-local reductions.
__device__ __forceinline__ int4 nt_load_i4(const int* p){
    vi4 v = __builtin_nontemporal_load((const vi4*)p);
    return make_int4(v.x, v.y, v.z, v.w);
}

// add 8 halfs (16B) into fp32 accumulator
__device__ __forceinline__ void addrow8(float* a, float4 v){
    const __half2* p = (const __half2*)&v;
#pragma unroll
    for (int k = 0; k < 4; k++){
        float2 f = __half22float2(p[k]);
        a[2*k] += f.x; a[2*k+1] += f.y;
    }
}
// packed fp16 add of two 8-half rows
__device__ __forceinline__ float4 h2add4f(float4 a, float4 b){
    __half2* pa = (__half2*)&a; __half2* pb = (__half2*)&b;
    float4 r; __half2* pr = (__half2*)&r;
#pragma unroll
    for (int k = 0; k < 4; k++) pr[k] = __hadd2(pa[k], pb[k]);
    return r;
}

// ===== fused: edge binning (single pass from regs) | input MLP + BN stats ===
// bin blocks FIRST in the grid so their latency overlaps MLP compute.
union SMem {
    struct {
        float sW1[3*HF]; float sB1[HF]; float sW2[HF*HF]; float sB2[HF];
        float sh[256][33];
    } mlp;
    struct { int lcnt[1024]; int lbase[1024]; int lpos[1024]; } bin;
};

__global__ __launch_bounds__(256)
void k_mlp_bin(const float* __restrict__ x,
               const float* __restrict__ w1, const float* __restrict__ b1,
               const float* __restrict__ w2, const float* __restrict__ b2,
               __half* __restrict__ h, float* __restrict__ stats,
               const int* __restrict__ src, const int* __restrict__ dst,
               int* __restrict__ gfill, int* __restrict__ ep,
               int N, int E, int B, int NC){
    __shared__ SMem sm;
    int t = threadIdx.x;
    if ((int)blockIdx.x < NC){
        // ---------------- binning: single pass, chunk held in regs --------
        int bid = blockIdx.x;
        for (int i = t; i < B; i += 256){ sm.bin.lcnt[i] = 0; sm.bin.lpos[i] = 0; }
        __syncthreads();
        int base = bid * CH;
        int xcd = bid & 7;
        int dv[16], sv[16];
        if (base + CH <= E){
#pragma unroll
            for (int i = 0; i < 4; i++){
                int4 d4 = nt_load_i4(dst + base + (t + i*256)*4);
                int4 s4 = nt_load_i4(src + base + (t + i*256)*4);
                dv[4*i]   = d4.x; dv[4*i+1] = d4.y; dv[4*i+2] = d4.z; dv[4*i+3] = d4.w;
                sv[4*i]   = s4.x; sv[4*i+1] = s4.y; sv[4*i+2] = s4.z; sv[4*i+3] = s4.w;
            }
        } else {
#pragma unroll
            for (int i = 0; i < 16; i++){
                int e = base + t + i*256;
                dv[i] = (e < E) ? dst[e] : -1;
                sv[i] = (e < E) ? src[e] : 0;
            }
        }
#pragma unroll
        for (int i = 0; i < 16; i++)
            if (dv[i] >= 0) atomicAdd(&sm.bin.lcnt[dv[i] >> BSH], 1);
        __syncthreads();
        // reserve contiguous range in this block's xcd sub-segment per bucket
        for (int i = t; i < B; i += 256){
            int c = sm.bin.lcnt[i];
            sm.bin.lbase[i] = c ? (i*CAP + xcd*SUBCAP + atomicAdd(&gfill[i*8 + xcd], c)) : 0;
        }
        __syncthreads();
        // scatter straight from registers (no re-read)
#pragma unroll
        for (int i = 0; i < 16; i++)
            if (dv[i] >= 0){
                int bb = dv[i] >> BSH;
                int p = sm.bin.lbase[bb] + atomicAdd(&sm.bin.lpos[bb], 1);
                ep[p] = (sv[i] << BSH) | (dv[i] & (BSZ-1));
            }
    } else {
        // ---------------- MLP + BN stats ----------------
        for (int i = t; i < 3*HF; i += 256) sm.mlp.sW1[i] = w1[i];
        if (t < HF){ sm.mlp.sB1[t] = b1[t]; sm.mlp.sB2[t] = b2[t]; }
        for (int i = t; i < HF*HF; i += 256) sm.mlp.sW2[i] = w2[i];
        __syncthreads();
        int n = (blockIdx.x - NC)*256 + t;
        float h2[HF];
        if (n < N){
            float x0 = x[(size_t)n*3], x1 = x[(size_t)n*3+1], x2 = x[(size_t)n*3+2];
            float h1[HF];
#pragma unroll
            for (int j = 0; j < HF; j++){
                float v = fmaf(x0, sm.mlp.sW1[j], fmaf(x1, sm.mlp.sW1[HF+j],
                          fmaf(x2, sm.mlp.sW1[2*HF+j], sm.mlp.sB1[j])));
                h1[j] = leaky(v);
            }
#pragma unroll
            for (int j = 0; j < HF; j++){
                float v = sm.mlp.sB2[j];
#pragma unroll
                for (int i = 0; i < HF; i++) v = fmaf(h1[i], sm.mlp.sW2[i*HF+j], v);
                h2[j] = leaky(v);
            }
            float4* hv = (float4*)(h + (size_t)n*HF);
#pragma unroll
            for (int jb = 0; jb < 4; jb++){
                __half2 hh[4];
#pragma unroll
                for (int k = 0; k < 4; k++)
                    hh[k] = __float22half2_rn(make_float2(h2[jb*8+2*k], h2[jb*8+2*k+1]));
                hv[jb] = *(float4*)hh;
            }
        } else {
#pragma unroll
            for (int j = 0; j < HF; j++) h2[j] = 0.f;
        }
#pragma unroll
        for (int j = 0; j < HF; j++) sm.mlp.sh[t][j] = h2[j];
        __syncthreads();
        int f = t & 31, g = t >> 5;
        float s = 0.f, ss = 0.f;
        for (int i = 0; i < 32; i++){
            float v = sm.mlp.sh[g*32 + i][f];
            s += v; ss += v*v;
        }
        __syncthreads();
        sm.mlp.sh[g][f] = s; sm.mlp.sh[8+g][f] = ss;
        __syncthreads();
        if (t < HF){
            float a = 0.f, b = 0.f;
#pragma unroll
            for (int g2 = 0; g2 < 8; g2++){ a += sm.mlp.sh[g2][t]; b += sm.mlp.sh[8+g2][t]; }
            atomicAdd(&stats[t], a);
            atomicAdd(&stats[HF+t], b);
        }
    }
}

// ===== fused per-bucket: CSR build + BN + t1 ===============================
// One block per bucket. lcnt[t] (LDS count over the bucket's own edges) IS
// deg[n] for n = b*128+t — no global deg array. After the scatter, ALL 256
// threads run BN + (h@W1)*dis: 2 threads per node, 16 output features each.
__global__ __launch_bounds__(256)
void k_csr_t1(int* __restrict__ ep, const int* __restrict__ gfill,
              int2* __restrict__ rowp2, float* __restrict__ dis,
              const __half* __restrict__ h, const float* __restrict__ stats,
              const float* __restrict__ gamma, const float* __restrict__ beta,
              const float* __restrict__ W, __half* __restrict__ tout,
              int N, int B){
    __shared__ int sep[CAP];
    __shared__ int lcnt[128], lpre[128], lfill[128];
    __shared__ float sW[HF*HF];
    __shared__ float sscale[HF], sshift[HF];
    int t = threadIdx.x;
    int b = blockIdx.x;
    for (int i = t; i < HF*HF; i += 256) sW[i] = W[i];
    if (t < HF){
        float inv = 1.0f/(float)N;
        float mu  = stats[t]*inv;
        float var = stats[HF+t]*inv - mu*mu;
        float rs  = rsqrtf(var + EPS);
        float sc  = rs*gamma[t];
        sscale[t] = sc;
        sshift[t] = beta[t] - mu*sc;
    }
    if (t < 128){ lcnt[t] = 0; lfill[t] = 0; }
    int cx[8], coff[8], cnt = 0;
#pragma unroll
    for (int xx = 0; xx < 8; xx++){ cx[xx] = gfill[b*8 + xx]; coff[xx] = cnt; cnt += cx[xx]; }
    int base = b*CAP;
    __syncthreads();
#pragma unroll
    for (int xx = 0; xx < 8; xx++)
        for (int j = t; j < cx[xx]; j += 256) sep[coff[xx] + j] = ep[base + xx*SUBCAP + j];
    __syncthreads();
    for (int e = t; e < cnt; e += 256) atomicAdd(&lcnt[sep[e] & (BSZ-1)], 1);
    __syncthreads();
    if (t < 128){
        int dg = lcnt[t];
        int pre = 0;
        for (int j = 0; j < t; j++) pre += lcnt[j];    // LDS broadcast loop
        lpre[t] = pre;
        int n = b*BSZ + t;
        if (n < N){
            rowp2[n] = make_int2(base + pre, base + pre + dg);
            dis[n]   = rsqrtf((float)dg + 1.0f);
        }
    }
    __syncthreads();
    for (int e = t; e < cnt; e += 256){
        int val = sep[e];
        int d = val & (BSZ-1);
        int p = lpre[d] + atomicAdd(&lfill[d], 1);
        ep[base + p] = val >> BSH;                     // strip -> plain src index
    }
    // ------- BN + t1: 2 threads per node, 16 output features each ----------
    int nloc = t >> 1, fh = (t & 1) * 16;
    int n = b*BSZ + nloc;
    if (n < N){
        float dloc = rsqrtf((float)lcnt[nloc] + 1.0f);
        const float4* hv4 = (const float4*)h + (size_t)n*4;
        float v[HF];
#pragma unroll
        for (int k = 0; k < 4; k++){
            float4 raw = hv4[k];
            const __half2* p2 = (const __half2*)&raw;
#pragma unroll
            for (int q = 0; q < 4; q++){
                float2 f2 = __half22float2(p2[q]);
                v[8*k + 2*q]     = f2.x;
                v[8*k + 2*q + 1] = f2.y;
            }
        }
#pragma unroll
        for (int f = 0; f < HF; f++) v[f] = fmaf(v[f], sscale[f], sshift[f]);
        float o[16];
#pragma unroll
        for (int j = 0; j < 16; j++) o[j] = 0.f;
#pragma unroll
        for (int i = 0; i < HF; i++){
            float vi = v[i];
#pragma unroll
            for (int j4 = 0; j4 < 4; j4++){
                float4 w4 = *(const float4*)&sW[i*HF + fh + 4*j4];
                o[4*j4]   = fmaf(vi, w4.x, o[4*j4]);
                o[4*j4+1] = fmaf(vi, w4.y, o[4*j4+1]);
                o[4*j4+2] = fmaf(vi, w4.z, o[4*j4+2]);
                o[4*j4+3] = fmaf(vi, w4.w, o[4*j4+3]);
            }
        }
        float4* ov = (float4*)tout + (size_t)n*4 + (t & 1)*2;
#pragma unroll
        for (int k = 0; k < 2; k++){
            __half2 hh[4];
#pragma unroll
            for (int q = 0; q < 4; q++)
                hh[q] = __float22half2_rn(make_float2(o[8*k+2*q]*dloc, o[8*k+2*q+1]*dloc));
            ov[k] = *(float4*)hh;
        }
    }
}

// ------- per-node gather: 32 nodes/block, 8 lanes/node (2 edge-halves) ------
// Two 4-lane groups per node split the edge list into even/odd 4-edge chunks;
// partial sums combined with one shfl_xor(4). 2x grid + halved latency chain.
__global__ __launch_bounds__(256)
void k_gather_t(const __half* __restrict__ tin, const int* __restrict__ esrc,
                const int2* __restrict__ rowp2, const float* __restrict__ dis,
                const float* __restrict__ bias, const float* __restrict__ W,
                __half* __restrict__ tout, int N){
    __shared__ float sW[HF*HF];
    __shared__ float sh[32][33];
    int tid = threadIdx.x;
    for (int i = tid; i < HF*HF; i += 256) sW[i] = W[i];
    int node = tid >> 3, l2 = tid & 7, l = l2 & 3, hf = l2 >> 2;
    int n = blockIdx.x*32 + node;
    float acc[8] = {0.f,0.f,0.f,0.f,0.f,0.f,0.f,0.f};
    float d = 0.f;
    const float4* tv = (const float4*)tin;
    if (n < N){
        if (hf == 0) addrow8(acc, tv[(size_t)n*4 + l]);      // self loop
        int2 r = rowp2[n];
        int e0 = r.x, e1 = r.y;
        int ea = (e0 + 3) & ~3; if (ea > e1) ea = e1;
        if (hf == 0) for (int e = e0; e < ea; e++) addrow8(acc, tv[(size_t)esrc[e]*4 + l]);
        int nch = (e1 - ea) >> 2;          // full 4-edge chunks
        int c = hf;
        for (; c + 2 < nch; c += 4){       // two chunks of this parity: 8 loads in flight
            int4 a4 = nt_load_i4(&esrc[ea + 4*c]);
            int4 b4 = nt_load_i4(&esrc[ea + 4*(c+2)]);
            float4 v0 = tv[(size_t)a4.x*4 + l];
            float4 v1 = tv[(size_t)a4.y*4 + l];
            float4 v2 = tv[(size_t)a4.z*4 + l];
            float4 v3 = tv[(size_t)a4.w*4 + l];
            float4 v4 = tv[(size_t)b4.x*4 + l];
            float4 v5 = tv[(size_t)b4.y*4 + l];
            float4 v6 = tv[(size_t)b4.z*4 + l];
            float4 v7 = tv[(size_t)b4.w*4 + l];
            addrow8(acc, h2add4f(h2add4f(v0, v1), h2add4f(v2, v3)));
            addrow8(acc, h2add4f(h2add4f(v4, v5), h2add4f(v6, v7)));
        }
        for (; c < nch; c += 2){
            int4 s4 = nt_load_i4(&esrc[ea + 4*c]);
            float4 v0 = tv[(size_t)s4.x*4 + l];
            float4 v1 = tv[(size_t)s4.y*4 + l];
            float4 v2 = tv[(size_t)s4.z*4 + l];
            float4 v3 = tv[(size_t)s4.w*4 + l];
            addrow8(acc, h2add4f(h2add4f(v0, v1), h2add4f(v2, v3)));
        }
        if (hf == 1) for (int e = ea + 4*nch; e < e1; e++) addrow8(acc, tv[(size_t)esrc[e]*4 + l]);
        // combine the two edge-halves: lanes l and l^4 hold partial sums
#pragma unroll
        for (int cc = 0; cc < 8; cc++) acc[cc] += __shfl_xor(acc[cc], 4);
        d = dis[n];
#pragma unroll
        for (int cc = 0; cc < 8; cc++)
            acc[cc] = elu1(fmaf(d, acc[cc], bias[8*l + cc]));
    }
    __syncthreads();
    if (hf == 0){
#pragma unroll
        for (int cc = 0; cc < 8; cc++) sh[node][8*l + cc] = acc[cc];
    }
    __syncthreads();
    // transform: each of the 8 lanes computes 4 output features
    float o[4] = {0.f,0.f,0.f,0.f};
#pragma unroll
    for (int i = 0; i < HF; i++){
        float hvv = sh[node][i];
        float4 w4 = *(const float4*)&sW[i*HF + 4*l2];
        o[0] = fmaf(hvv, w4.x, o[0]); o[1] = fmaf(hvv, w4.y, o[1]);
        o[2] = fmaf(hvv, w4.z, o[2]); o[3] = fmaf(hvv, w4.w, o[3]);
    }
    if (n < N){
        __half2 hh[2];
        hh[0] = __float22half2_rn(make_float2(o[0]*d, o[1]*d));
        hh[1] = __float22half2_rn(make_float2(o[2]*d, o[3]*d));
        ((float2*)tout)[(size_t)n*8 + l2] = *(float2*)hh;
    }
}

// ------- final: gather layer3 + elu, output MLP + sigmoid col 0 -------------
__global__ __launch_bounds__(256)
void k_gather_out(const __half* __restrict__ tin, const int* __restrict__ esrc,
                  const int2* __restrict__ rowp2, const float* __restrict__ dis,
                  const float* __restrict__ bg3,
                  const float* __restrict__ wo1, const float* __restrict__ bo1,
                  const float* __restrict__ wo2, const float* __restrict__ bo2,
                  const float* __restrict__ wo3, const float* __restrict__ bo3,
                  float* __restrict__ out, int N){
    __shared__ float sW1[HF*HF], sW2[HF*HF], sW3[HF*4];
    __shared__ float sh[32][33], sh2[32][33];
    int tid = threadIdx.x;
    for (int i = tid; i < HF*HF; i += 256){ sW1[i] = wo1[i]; sW2[i] = wo2[i]; }
    if (tid < HF*4) sW3[tid] = wo3[tid];
    int node = tid >> 3, l2 = tid & 7, l = l2 & 3, hf = l2 >> 2;
    int n = blockIdx.x*32 + node;
    float acc[8] = {0.f,0.f,0.f,0.f,0.f,0.f,0.f,0.f};
    const float4* tv = (const float4*)tin;
    if (n < N){
        if (hf == 0) addrow8(acc, tv[(size_t)n*4 + l]);
        int2 r = rowp2[n];
        int e0 = r.x, e1 = r.y;
        int ea = (e0 + 3) & ~3; if (ea > e1) ea = e1;
        if (hf == 0) for (int e = e0; e < ea; e++) addrow8(acc, tv[(size_t)esrc[e]*4 + l]);
        int nch = (e1 - ea) >> 2;
        int c = hf;
        for (; c + 2 < nch; c += 4){
            int4 a4 = nt_load_i4(&esrc[ea + 4*c]);
            int4 b4 = nt_load_i4(&esrc[ea + 4*(c+2)]);
            float4 v0 = tv[(size_t)a4.x*4 + l];
            float4 v1 = tv[(size_t)a4.y*4 + l];
            float4 v2 = tv[(size_t)a4.z*4 + l];
            float4 v3 = tv[(size_t)a4.w*4 + l];
            float4 v4 = tv[(size_t)b4.x*4 + l];
            float4 v5 = tv[(size_t)b4.y*4 + l];
            float4 v6 = tv[(size_t)b4.z*4 + l];
            float4 v7 = tv[(size_t)b4.w*4 + l];
            addrow8(acc, h2add4f(h2add4f(v0, v1), h2add4f(v2, v3)));
            addrow8(acc, h2add4f(h2add4f(v4, v5), h2add4f(v6, v7)));
        }
        for (; c < nch; c += 2){
            int4 s4 = nt_load_i4(&esrc[ea + 4*c]);
            float4 v0 = tv[(size_t)s4.x*4 + l];
            float4 v1 = tv[(size_t)s4.y*4 + l];
            float4 v2 = tv[(size_t)s4.z*4 + l];
            float4 v3 = tv[(size_t)s4.w*4 + l];
            addrow8(acc, h2add4f(h2add4f(v0, v1), h2add4f(v2, v3)));
        }
        if (hf == 1) for (int e = ea + 4*nch; e < e1; e++) addrow8(acc, tv[(size_t)esrc[e]*4 + l]);
#pragma unroll
        for (int cc = 0; cc < 8; cc++) acc[cc] += __shfl_xor(acc[cc], 4);
        float d = dis[n];
#pragma unroll
        for (int cc = 0; cc < 8; cc++)
            acc[cc] = elu1(fmaf(d, acc[cc], bg3[8*l + cc]));
    }
    __syncthreads();
    if (hf == 0){
#pragma unroll
        for (int cc = 0; cc < 8; cc++) sh[node][8*l + cc] = acc[cc];
    }
    __syncthreads();
    // o1: each lane 4 features
    float o1[4];
#pragma unroll
    for (int cc = 0; cc < 4; cc++) o1[cc] = bo1[4*l2 + cc];
#pragma unroll
    for (int i = 0; i < HF; i++){
        float hvv = sh[node][i];
        float4 w4 = *(const float4*)&sW1[i*HF + 4*l2];
        o1[0] = fmaf(hvv, w4.x, o1[0]); o1[1] = fmaf(hvv, w4.y, o1[1]);
        o1[2] = fmaf(hvv, w4.z, o1[2]); o1[3] = fmaf(hvv, w4.w, o1[3]);
    }
#pragma unroll
    for (int cc = 0; cc < 4; cc++) sh2[node][4*l2 + cc] = leaky(o1[cc]);
    __syncthreads();
    float o2[4];
#pragma unroll
    for (int cc = 0; cc < 4; cc++) o2[cc] = bo2[4*l2 + cc];
#pragma unroll
    for (int i = 0; i < HF; i++){
        float hvv = sh2[node][i];
        float4 w4 = *(const float4*)&sW2[i*HF + 4*l2];
        o2[0] = fmaf(hvv, w4.x, o2[0]); o2[1] = fmaf(hvv, w4.y, o2[1]);
        o2[2] = fmaf(hvv, w4.z, o2[2]); o2[3] = fmaf(hvv, w4.w, o2[3]);
    }
    __syncthreads();
#pragma unroll
    for (int cc = 0; cc < 4; cc++) sh[node][4*l2 + cc] = leaky(o2[cc]);
    __syncthreads();
    if (n < N && l2 < 4){
        float v = bo3[l2];
#pragma unroll
        for (int i = 0; i < HF; i++) v = fmaf(sh[node][i], sW3[i*4 + l2], v);
        if (l2 == 0) v = sigmoidf(v);
        out[(size_t)n*4 + l2] = v;
    }
}

extern "C" void kernel_launch(void* const* d_in, const int* in_sizes, int n_in,
                              void* d_out, int out_size, void* d_ws, size_t ws_size,
                              hipStream_t stream) {
    const float* x     = (const float*)d_in[0];
    const float* w_in1 = (const float*)d_in[1];
    const float* b_in1 = (const float*)d_in[2];
    const float* w_in2 = (const float*)d_in[3];
    const float* b_in2 = (const float*)d_in[4];
    const float* gamma = (const float*)d_in[5];
    const float* beta  = (const float*)d_in[6];
    const float* wg1   = (const float*)d_in[7];
    const float* bg1   = (const float*)d_in[8];
    const float* wg2   = (const float*)d_in[9];
    const float* bg2   = (const float*)d_in[10];
    const float* wg3   = (const float*)d_in[11];
    const float* bg3   = (const float*)d_in[12];
    const float* wo1   = (const float*)d_in[13];
    const float* bo1   = (const float*)d_in[14];
    const float* wo2   = (const float*)d_in[15];
    const float* bo2   = (const float*)d_in[16];
    const float* wo3   = (const float*)d_in[17];
    const float* bo3   = (const float*)d_in[18];
    const int*   ei    = (const int*)d_in[19];

    int N = in_sizes[0] / 3;
    int E = in_sizes[19] / 2;
    int B = (N + BSZ - 1) >> BSH;          // buckets (782; lcnt arrays hold 1024)

    char* w = (char*)d_ws;
    size_t o = 0;
    auto alloc = [&](size_t bytes){ size_t r = o; o = (o + bytes + 255) & ~(size_t)255; return r; };
    // ---- zeroed region ----
    float* stats = (float*)(w + alloc(2*HF*sizeof(float)));
    int*   gfill = (int*)  (w + alloc((size_t)B*8*4));
    size_t zero_bytes = o;
    // ---- rest ----
    int2*  rowp2 = (int2*) (w + alloc((size_t)N*8));
    float* dis   = (float*)(w + alloc((size_t)N*4));
    int*   ep    = (int*)  (w + alloc((size_t)B*CAP*4));
    __half* bufH = (__half*)(w + alloc((size_t)N*HF*2));
    __half* tA   = (__half*)(w + alloc((size_t)N*HF*2));
    __half* tB   = (__half*)(w + alloc((size_t)N*HF*2));

    hipMemsetAsync(d_ws, 0, zero_bytes, stream);

    const int* src = ei;
    const int* dst = ei + E;
    int NB1 = (N + 255) / 256;
    int NC  = (E + CH - 1) / CH;
    int GN  = (N + 31) / 32;               // 32 nodes per gather block

    k_mlp_bin<<<NC + NB1, 256, 0, stream>>>(x, w_in1, b_in1, w_in2, b_in2, bufH, stats,
                                            src, dst, gfill, ep, N, E, B, NC);
    k_csr_t1<<<B, 256, 0, stream>>>(ep, gfill, rowp2, dis,
                                    bufH, stats, gamma, beta, wg1, tA, N, B);
    k_gather_t<<<GN, 256, 0, stream>>>(tA, ep, rowp2, dis, bg1, wg2, tB, N);
    k_gather_t<<<GN, 256, 0, stream>>>(tB, ep, rowp2, dis, bg2, wg3, tA, N);
    k_gather_out<<<GN, 256, 0, stream>>>(tA, ep, rowp2, dis, bg3,
                                         wo1, bo1, wo2, bo2, wo3, bo3, (float*)d_out, N);
}